// Round 1
// 391.909 us; speedup vs baseline: 1.0964x; 1.0964x over previous
//
#include <hip/hip_runtime.h>
#include <cmath>

#define BB 16
#define CC 64
#define PP 16384   // H*W = 128*128

typedef float f32x4 __attribute__((ext_vector_type(4)));
typedef short bf16x8 __attribute__((ext_vector_type(8)));   // 8 bf16 = 4 VGPRs (MFMA A/B frag)
typedef int i32x4 __attribute__((ext_vector_type(4)));
typedef unsigned int u32;

// ---------------------------------------------------------------------------
// Kernel 1: channel means. grid = B*4*C = 4096 blocks, one 64 KiB plane each.
// ---------------------------------------------------------------------------
__global__ __launch_bounds__(256) void k_means(const float* __restrict__ low,
                                               const float* __restrict__ high,
                                               const float* __restrict__ flow,
                                               const float* __restrict__ fb,
                                               float* __restrict__ cf) {
    int blk = blockIdx.x;                  // b*256 + t*64 + c
    int b = blk >> 8, t = (blk >> 6) & 3, c = blk & 63;
    const float* in = (t == 0) ? low : (t == 1) ? high : (t == 2) ? flow : fb;
    const float4* p = (const float4*)(in + ((size_t)(b * CC + c)) * PP);
    int tid = threadIdx.x;

    float s = 0.f;
    #pragma unroll
    for (int i = 0; i < 16; ++i) {
        float4 v = p[tid + i * 256];
        s += (v.x + v.y) + (v.z + v.w);
    }
    #pragma unroll
    for (int off = 32; off > 0; off >>= 1) s += __shfl_down(s, off, 64);

    __shared__ float r[4];
    if ((tid & 63) == 0) r[tid >> 6] = s;
    __syncthreads();
    if (tid == 0)
        cf[(b * 4 + t) * CC + c] = ((r[0] + r[1]) + (r[2] + r[3])) * (1.0f / PP);
}

// ---------------------------------------------------------------------------
// Kernel 2: adjacency + GCN + SE heads + effective mixing matrices.
// grid = B blocks, 256 threads. Amat[b][t][c][o], o contiguous.
// ---------------------------------------------------------------------------
__global__ __launch_bounds__(256) void k_small(const float* __restrict__ cf,
    const float* __restrict__ Wgcn, const float* __restrict__ bgcn,
    const float* __restrict__ W1, const float* __restrict__ b1,
    const float* __restrict__ W2, const float* __restrict__ b2,
    const float* __restrict__ W3, const float* __restrict__ b3,
    const float* __restrict__ W4, const float* __restrict__ b4,
    const float* __restrict__ Wgate,
    float* __restrict__ Amat) {
    int b = blockIdx.x;
    int tid = threadIdx.x;
    int lane = tid & 63;
    int wid = tid >> 6;                    // wave-uniform
    __shared__ float x[4][64];
    __shared__ float nrm[4];
    __shared__ float adj[16];
    __shared__ float y[4][64];
    __shared__ float fc[256];
    __shared__ float e[4][64];

    x[wid][lane] = cf[b * 256 + tid];
    __syncthreads();

    if (tid < 4) {
        float s = 0.f;
        for (int c = 0; c < 64; ++c) s += x[tid][c] * x[tid][c];
        nrm[tid] = sqrtf(s);
    }
    __syncthreads();

    if (tid < 16) {
        int i = tid >> 2, j = tid & 3;
        float s = 0.f;
        for (int c = 0; c < 64; ++c) s += x[i][c] * x[j][c];
        adj[tid] = s / (nrm[i] * nrm[j]);
    }
    __syncthreads();

    {   // y = adj @ x
        float s = 0.f;
        #pragma unroll
        for (int j = 0; j < 4; ++j) s += adj[wid * 4 + j] * x[j][lane];
        y[wid][lane] = s;
    }
    __syncthreads();

    {   // fc = relu(y @ Wgcn + bgcn)
        float s = bgcn[lane];
        for (int c = 0; c < 64; ++c) s += y[wid][c] * Wgcn[c * 64 + lane];
        fc[wid * 64 + lane] = fmaxf(s, 0.f);
    }
    __syncthreads();

    {   // e_k = sigmoid(fc @ Wk^T + bk); wave wid handles head wid.
        const float* Wk = (wid == 0) ? W1 : (wid == 1) ? W2 : (wid == 2) ? W3 : W4;
        const float* bk = (wid == 0) ? b1 : (wid == 1) ? b2 : (wid == 2) ? b3 : b4;
        float4 fv = *(const float4*)&fc[lane * 4];
        for (int c = 0; c < 64; ++c) {
            float4 w = *(const float4*)(Wk + c * 256 + lane * 4);
            float part = (w.x * fv.x + w.y * fv.y) + (w.z * fv.z + w.w * fv.w);
            #pragma unroll
            for (int off = 32; off > 0; off >>= 1)
                part += __shfl_down(part, off, 64);
            if (lane == 0) {
                float s = part + bk[c];
                e[wid][c] = 1.f / (1.f + expf(-s));
            }
        }
    }
    __syncthreads();

    // A[t][c][o] = Wg[o,t*64+c] + e[t][c]*(sum_q Wg[o,q*64+c] - Wg[o,t*64+c])
    {
        int t = wid, o = lane;
        const float* wrow = Wgate + o * 256;
        float* Ab = Amat + b * 16384 + t * 4096;
        #pragma unroll 4
        for (int c4 = 0; c4 < 64; c4 += 4) {
            float4 w0 = *(const float4*)(wrow + c4);
            float4 w1 = *(const float4*)(wrow + 64 + c4);
            float4 w2 = *(const float4*)(wrow + 128 + c4);
            float4 w3 = *(const float4*)(wrow + 192 + c4);
            float4 wt = (t == 0) ? w0 : (t == 1) ? w1 : (t == 2) ? w2 : w3;
            float4 sm = make_float4((w0.x + w1.x) + (w2.x + w3.x),
                                    (w0.y + w1.y) + (w2.y + w3.y),
                                    (w0.z + w1.z) + (w2.z + w3.z),
                                    (w0.w + w1.w) + (w2.w + w3.w));
            Ab[(c4 + 0) * 64 + o] = wt.x + e[t][c4 + 0] * (sm.x - wt.x);
            Ab[(c4 + 1) * 64 + o] = wt.y + e[t][c4 + 1] * (sm.y - wt.y);
            Ab[(c4 + 2) * 64 + o] = wt.z + e[t][c4 + 2] * (sm.z - wt.z);
            Ab[(c4 + 3) * 64 + o] = wt.w + e[t][c4 + 3] * (sm.w - wt.w);
        }
    }
}

// ---------------------------------------------------------------------------
// Kernel 3 (MFMA rewrite): out[b,o,p] = sum_k A2[k,o]*X[k,p] + bgate[o],
// k = t*64+c (K=256), via mfma_f32_16x16x32_bf16 with bf16 hi/lo split
// (3 products: Ah*Xh + Ah*Xl + Al*Xh -> fp32-class accuracy).
// grid = B*64 blocks (256 px/tile), 256 thr = 4 waves; each wave owns
// 64 pixels x all 64 outputs (4 o-tiles x 4 p-tiles) -> X fetched once.
// Fragment gather: per load instr, each 16-lane group reads 64B contiguous;
// the 4 p-tiles cover 256B of each k-row within the same chunk.
// A (64 KiB/batch) is L2-resident across the 64 blocks sharing it.
// ---------------------------------------------------------------------------
__device__ __forceinline__ void split_pair(float v0, float v1, u32& hi, u32& lo) {
    // hi = trunc-to-bf16 pair packed (elem0 in low half), lo = bf16(v - hi) pair.
    // v = hi + lo exact to ~2^-25 rel; 3-product MFMA covers cross terms.
    u32 u0 = __builtin_bit_cast(u32, v0);
    u32 u1 = __builtin_bit_cast(u32, v1);
    u32 h0 = u0 & 0xFFFF0000u;
    u32 h1 = u1 & 0xFFFF0000u;
    hi = (h0 >> 16) | h1;
    float l0 = v0 - __builtin_bit_cast(float, h0);
    float l1 = v1 - __builtin_bit_cast(float, h1);
    lo = (__builtin_bit_cast(u32, l0) >> 16) | (__builtin_bit_cast(u32, l1) & 0xFFFF0000u);
}

__global__ __launch_bounds__(256, 2) void k_gemm(const float* __restrict__ low,
    const float* __restrict__ high, const float* __restrict__ flow,
    const float* __restrict__ fb, const float* __restrict__ Amat,
    const float* __restrict__ bgate, float* __restrict__ out) {
    int blk = blockIdx.x;
    int b = blk >> 6;
    int tile = blk & 63;
    int tid = threadIdx.x;
    int lane = tid & 63;
    int wv = tid >> 6;                    // wave id: p-subrange of 64
    int l15 = lane & 15;
    int kq = (lane >> 4) << 3;            // quarter-wave k offset: 0,8,16,24

    int pbase = tile * 256 + wv * 64 + l15;        // p for p-tile 0 (col = lane&15)
    size_t xoff = (size_t)b * (CC * PP) + (size_t)kq * PP + pbase;
    const float* px[4] = {low + xoff, high + xoff, flow + xoff, fb + xoff};
    // A2[k][o] = Amat[b*16384 + k*64 + o]; fold kq and o-lane into base.
    const float* Ap = Amat + b * 16384 + kq * 64 + l15;

    f32x4 acc[4][4];                      // [o-tile][p-tile]
    #pragma unroll
    for (int i = 0; i < 4; ++i)
        #pragma unroll
        for (int j = 0; j < 4; ++j) acc[i][j] = (f32x4)(0.f);

    #pragma unroll
    for (int t = 0; t < 4; ++t) {
        const float* xp = px[t];
        #pragma unroll
        for (int h = 0; h < 2; ++h) {     // k-chunk of 32 within tensor t
            // ---- gather raw fp32 fragments (per lane: row kq+j, col l15) ----
            float xr[4][8];
            #pragma unroll
            for (int pt = 0; pt < 4; ++pt)
                #pragma unroll
                for (int j = 0; j < 8; ++j)
                    xr[pt][j] = xp[(size_t)(h * 32 + j) * PP + pt * 16];

            float ar[4][8];
            #pragma unroll
            for (int ot = 0; ot < 4; ++ot)
                #pragma unroll
                for (int j = 0; j < 8; ++j)
                    ar[ot][j] = Ap[(t * 64 + h * 32 + j) * 64 + ot * 16];

            // ---- split into bf16 hi/lo fragments (integer bit-surgery) ----
            bf16x8 xh[4], xl[4], ah[4], al[4];
            #pragma unroll
            for (int pt = 0; pt < 4; ++pt) {
                i32x4 hd, ld;
                #pragma unroll
                for (int d = 0; d < 4; ++d) {
                    u32 hi, lo;
                    split_pair(xr[pt][2 * d], xr[pt][2 * d + 1], hi, lo);
                    hd[d] = (int)hi; ld[d] = (int)lo;
                }
                xh[pt] = __builtin_bit_cast(bf16x8, hd);
                xl[pt] = __builtin_bit_cast(bf16x8, ld);
            }
            #pragma unroll
            for (int ot = 0; ot < 4; ++ot) {
                i32x4 hd, ld;
                #pragma unroll
                for (int d = 0; d < 4; ++d) {
                    u32 hi, lo;
                    split_pair(ar[ot][2 * d], ar[ot][2 * d + 1], hi, lo);
                    hd[d] = (int)hi; ld[d] = (int)lo;
                }
                ah[ot] = __builtin_bit_cast(bf16x8, hd);
                al[ot] = __builtin_bit_cast(bf16x8, ld);
            }

            // ---- 48 MFMAs: D[o][p] += A^T-slice * X-slice (K=32) ----
            #pragma unroll
            for (int ot = 0; ot < 4; ++ot)
                #pragma unroll
                for (int pt = 0; pt < 4; ++pt) {
                    acc[ot][pt] = __builtin_amdgcn_mfma_f32_16x16x32_bf16(
                        ah[ot], xh[pt], acc[ot][pt], 0, 0, 0);
                    acc[ot][pt] = __builtin_amdgcn_mfma_f32_16x16x32_bf16(
                        ah[ot], xl[pt], acc[ot][pt], 0, 0, 0);
                    acc[ot][pt] = __builtin_amdgcn_mfma_f32_16x16x32_bf16(
                        al[ot], xh[pt], acc[ot][pt], 0, 0, 0);
                }
        }
    }

    // ---- epilogue: C/D layout col=lane&15, row=(lane>>4)*4+reg ----
    int rg = lane >> 4;
    size_t obase = (size_t)b * (CC * PP) + (size_t)pbase;
    #pragma unroll
    for (int ot = 0; ot < 4; ++ot)
        #pragma unroll
        for (int r = 0; r < 4; ++r) {
            int o = ot * 16 + rg * 4 + r;
            float bg = bgate[o];
            #pragma unroll
            for (int pt = 0; pt < 4; ++pt)
                out[obase + (size_t)o * PP + pt * 16] = acc[ot][pt][r] + bg;
        }
}

extern "C" void kernel_launch(void* const* d_in, const int* in_sizes, int n_in,
                              void* d_out, int out_size, void* d_ws, size_t ws_size,
                              hipStream_t stream) {
    const float* low  = (const float*)d_in[0];
    const float* high = (const float*)d_in[1];
    const float* flow = (const float*)d_in[2];
    const float* fb   = (const float*)d_in[3];
    const float* Wgcn = (const float*)d_in[4];
    const float* bgcn = (const float*)d_in[5];
    const float* W1   = (const float*)d_in[6];
    const float* b1   = (const float*)d_in[7];
    const float* W2   = (const float*)d_in[8];
    const float* b2   = (const float*)d_in[9];
    const float* W3   = (const float*)d_in[10];
    const float* b3   = (const float*)d_in[11];
    const float* W4   = (const float*)d_in[12];
    const float* b4   = (const float*)d_in[13];
    const float* Wgate = (const float*)d_in[14];
    const float* bgate = (const float*)d_in[15];
    float* out = (float*)d_out;

    float* cf   = (float*)d_ws;          // [16][4][64]
    float* Amat = (float*)d_ws + 4096;   // [16][4][64][64]

    k_means<<<BB * 4 * CC, 256, 0, stream>>>(low, high, flow, fb, cf);
    k_small<<<BB, 256, 0, stream>>>(cf, Wgcn, bgcn, W1, b1, W2, b2, W3, b3,
                                    W4, b4, Wgate, Amat);
    k_gemm<<<BB * CC, 256, 0, stream>>>(low, high, flow, fb, Amat, bgate, out);
}